// Round 1
// baseline (3064.929 us; speedup 1.0000x reference)
//
#include <hip/hip_runtime.h>
#include <hip/hip_bf16.h>

#define N_NODES 100000
#define N_EDGES 1600000
#define F_IN 165
#define HID 128

// ---------------- CSR build ----------------

__global__ __launch_bounds__(256) void k_hist(const int* __restrict__ dst, int E, int* __restrict__ cnt) {
    int e = blockIdx.x * 256 + threadIdx.x;
    if (e < E) atomicAdd(&cnt[dst[e]], 1);
}

// per-block inclusive scan -> exclusive within block + block totals
__global__ __launch_bounds__(512) void k_scan1(const int* __restrict__ deg, int* __restrict__ rowptr,
                                               int* __restrict__ bsum, int N) {
    __shared__ int tmp[512];
    int t = threadIdx.x;
    int i = blockIdx.x * 512 + t;
    int v = (i < N) ? deg[i] : 0;
    tmp[t] = v;
    __syncthreads();
    for (int off = 1; off < 512; off <<= 1) {
        int x = (t >= off) ? tmp[t - off] : 0;
        __syncthreads();
        tmp[t] += x;
        __syncthreads();
    }
    if (i < N) rowptr[i] = tmp[t] - v;  // exclusive
    if (t == 511) bsum[blockIdx.x] = tmp[511];
}

__global__ __launch_bounds__(256) void k_scan2(const int* __restrict__ bsum, int* __restrict__ boff, int nb) {
    __shared__ int tmp[256];
    int t = threadIdx.x;
    int v = (t < nb) ? bsum[t] : 0;
    tmp[t] = v;
    __syncthreads();
    for (int off = 1; off < 256; off <<= 1) {
        int x = (t >= off) ? tmp[t - off] : 0;
        __syncthreads();
        tmp[t] += x;
        __syncthreads();
    }
    if (t < nb) boff[t] = tmp[t] - v;  // exclusive
}

__global__ __launch_bounds__(512) void k_scan3(int* __restrict__ rowptr, const int* __restrict__ boff,
                                               int* __restrict__ cursor, int N, int E) {
    int i = blockIdx.x * 512 + threadIdx.x;
    if (i < N) {
        int v = rowptr[i] + boff[blockIdx.x];
        rowptr[i] = v;
        cursor[i] = v;
    }
    if (i == 0) rowptr[N] = E;
}

__global__ __launch_bounds__(256) void k_scatter(const int* __restrict__ src, const int* __restrict__ dst,
                                                 int* __restrict__ cursor, int* __restrict__ esrc, int E) {
    int e = blockIdx.x * 256 + threadIdx.x;
    if (e < E) {
        int pos = atomicAdd(&cursor[dst[e]], 1);
        esrc[pos] = src[e];
    }
}

// ---------------- dual GEMM: Y = A @ Wl^T, R = A @ Wr^T ----------------
// A: [N, lda-major, K], Wl/Wr: [128, K] row-major, Y/R: [N,128]
#define BN 64
#define KT 32
#define WPAD 36  // row stride in floats: keeps float4 alignment, breaks bank-stride

__global__ __launch_bounds__(256) void k_gemm_dual(
    const float* __restrict__ A, int lda, int K,
    const float* __restrict__ Wl, const float* __restrict__ Wr,
    float* __restrict__ Y, float* __restrict__ R, int N)
{
    __shared__ float As[BN][WPAD];
    __shared__ float Ws[256][WPAD];
    int tid = threadIdx.x;
    int n0 = blockIdx.x * BN;
    int col = tid & 31;       // k within chunk
    int row = tid >> 5;       // 0..7
    int tm = tid & 15;        // m group
    int tn = tid >> 4;        // 0..15 node group

    float acc[4][16];
#pragma unroll
    for (int i = 0; i < 4; i++)
#pragma unroll
        for (int j = 0; j < 16; j++) acc[i][j] = 0.f;

    for (int k0 = 0; k0 < K; k0 += KT) {
        // stage A tile [64][32]
#pragma unroll
        for (int r = 0; r < BN; r += 8) {
            int gr = n0 + r + row;
            int gk = k0 + col;
            As[r + row][col] = (gr < N && gk < K) ? A[(size_t)gr * lda + gk] : 0.f;
        }
        // stage W tile [256][32]: rows 0-127 = Wl, 128-255 = Wr
#pragma unroll
        for (int r = 0; r < 256; r += 8) {
            int wr = r + row;
            int gk = k0 + col;
            const float* W = (wr < 128) ? Wl : Wr;
            Ws[wr][col] = (gk < K) ? W[(size_t)(wr & 127) * K + gk] : 0.f;
        }
        __syncthreads();
#pragma unroll
        for (int kk = 0; kk < KT; kk += 4) {
            float4 a[4];
#pragma unroll
            for (int i = 0; i < 4; i++)
                a[i] = *(const float4*)&As[tn + 16 * i][kk];
#pragma unroll
            for (int j = 0; j < 16; j++) {
                float4 w = *(const float4*)&Ws[tm + 16 * j][kk];
#pragma unroll
                for (int i = 0; i < 4; i++) {
                    acc[i][j] += a[i].x * w.x + a[i].y * w.y + a[i].z * w.z + a[i].w * w.w;
                }
            }
        }
        __syncthreads();
    }
#pragma unroll
    for (int i = 0; i < 4; i++) {
        int node = n0 + tn + 16 * i;
        if (node >= N) continue;
        size_t base = (size_t)node * HID;
#pragma unroll
        for (int j = 0; j < 16; j++) {
            int m = tm + 16 * j;
            float v = acc[i][j];
            if (m < HID) Y[base + m] = v;
            else         R[base + (m - HID)] = v;
        }
    }
}

// ---------------- fused aggregate + bias + root + (LN) + ReLU ----------------
// one wave (64 lanes) per node; each lane owns features lane and lane+64
__global__ __launch_bounds__(256) void k_aggregate(
    const float* __restrict__ Y, const float* __restrict__ Rm,
    const float* __restrict__ Hres,
    const int* __restrict__ rowptr, const int* __restrict__ esrc,
    const float* __restrict__ bias, float* __restrict__ Hout,
    int N, int mode)  // mode 0: relu only (layer 0); mode 1: residual+LN+relu
{
    int lane = threadIdx.x & 63;
    int node = blockIdx.x * 4 + (threadIdx.x >> 6);
    if (node >= N) return;
    int beg = rowptr[node], end = rowptr[node + 1];
    float s0 = 0.f, s1 = 0.f;
    for (int j = beg; j < end; ++j) {
        int s = esrc[j];
        const float* yr = Y + (size_t)s * HID;
        s0 += yr[lane];
        s1 += yr[lane + 64];
    }
    float deg = (float)(end - beg);
    float inv = 1.0f / fmaxf(deg, 1.0f);
    size_t base = (size_t)node * HID;
    float v0 = s0 * inv + bias[lane]      + Rm[base + lane];
    float v1 = s1 * inv + bias[lane + 64] + Rm[base + lane + 64];
    if (mode == 0) {
        Hout[base + lane]      = fmaxf(v0, 0.f);
        Hout[base + lane + 64] = fmaxf(v1, 0.f);
    } else {
        float z0 = v0 + Hres[base + lane];
        float z1 = v1 + Hres[base + lane + 64];
        float sum = z0 + z1;
#pragma unroll
        for (int off = 32; off; off >>= 1) sum += __shfl_xor(sum, off);
        float mu = sum * (1.f / 128.f);
        float d0 = z0 - mu, d1 = z1 - mu;
        float vs = d0 * d0 + d1 * d1;
#pragma unroll
        for (int off = 32; off; off >>= 1) vs += __shfl_xor(vs, off);
        float rstd = rsqrtf(vs * (1.f / 128.f) + 1e-5f);
        Hout[base + lane]      = fmaxf(d0 * rstd, 0.f);
        Hout[base + lane + 64] = fmaxf(d1 * rstd, 0.f);
    }
}

// ---------------- final linear 128 -> 2 ----------------
__global__ __launch_bounds__(256) void k_final(
    const float* __restrict__ Hf, const float* __restrict__ linW,
    const float* __restrict__ linb, float* __restrict__ out, int N)
{
    int lane = threadIdx.x & 63;
    int node = blockIdx.x * 4 + (threadIdx.x >> 6);
    if (node >= N) return;
    size_t base = (size_t)node * HID;
    float h0 = Hf[base + lane], h1 = Hf[base + lane + 64];
    float p0 = h0 * linW[lane]       + h1 * linW[lane + 64];
    float p1 = h0 * linW[128 + lane] + h1 * linW[128 + lane + 64];
#pragma unroll
    for (int off = 32; off; off >>= 1) {
        p0 += __shfl_xor(p0, off);
        p1 += __shfl_xor(p1, off);
    }
    if (lane == 0) {
        out[(size_t)node * 2 + 0] = p0 + linb[0];
        out[(size_t)node * 2 + 1] = p1 + linb[1];
    }
}

extern "C" void kernel_launch(void* const* d_in, const int* in_sizes, int n_in,
                              void* d_out, int out_size, void* d_ws, size_t ws_size,
                              hipStream_t stream) {
    const int N = N_NODES, E = N_EDGES;
    const float* x   = (const float*)d_in[0];   // [N,165]
    const int*   ei  = (const int*)d_in[1];     // [2,E]
    const float* Wl0 = (const float*)d_in[2];   // [128,165]
    const float* bl0 = (const float*)d_in[3];   // [128]
    const float* Wr0 = (const float*)d_in[4];   // [128,165]
    const float* Wl  = (const float*)d_in[5];   // [2,128,128]
    const float* bl  = (const float*)d_in[6];   // [2,128]
    const float* Wr  = (const float*)d_in[7];   // [2,128,128]
    const float* lW  = (const float*)d_in[8];   // [2,128]
    const float* lb  = (const float*)d_in[9];   // [2]
    float* out = (float*)d_out;

    const int* src = ei;
    const int* dst = ei + E;

    // workspace layout
    char* w = (char*)d_ws;
    float* Hbuf = (float*)w; w += (size_t)N * HID * sizeof(float);
    float* Ybuf = (float*)w; w += (size_t)N * HID * sizeof(float);
    float* Rbuf = (float*)w; w += (size_t)N * HID * sizeof(float);
    int* cursor = (int*)w;   w += (size_t)N * sizeof(int);
    int* rowptr = (int*)w;   w += (size_t)(N + 1) * sizeof(int);
    int* bsum   = (int*)w;   w += 256 * sizeof(int);
    int* boff   = (int*)w;   w += 256 * sizeof(int);
    int* esrc   = (int*)w;   w += (size_t)E * sizeof(int);

    const int nbScan = (N + 511) / 512;      // 196
    const int nbE    = (E + 255) / 256;      // 6250
    const int nbGemm = (N + BN - 1) / BN;    // 1563
    const int nbNode = (N + 3) / 4;          // 25000

    // CSR build
    hipMemsetAsync(cursor, 0, (size_t)N * sizeof(int), stream);
    k_hist<<<nbE, 256, 0, stream>>>(dst, E, cursor);
    k_scan1<<<nbScan, 512, 0, stream>>>(cursor, rowptr, bsum, N);
    k_scan2<<<1, 256, 0, stream>>>(bsum, boff, nbScan);
    k_scan3<<<nbScan, 512, 0, stream>>>(rowptr, boff, cursor, N, E);
    k_scatter<<<nbE, 256, 0, stream>>>(src, dst, cursor, esrc, E);

    // layer 0: x [N,165]
    k_gemm_dual<<<nbGemm, 256, 0, stream>>>(x, F_IN, F_IN, Wl0, Wr0, Ybuf, Rbuf, N);
    k_aggregate<<<nbNode, 256, 0, stream>>>(Ybuf, Rbuf, nullptr, rowptr, esrc, bl0, Hbuf, N, 0);

    // layer 1
    k_gemm_dual<<<nbGemm, 256, 0, stream>>>(Hbuf, HID, HID, Wl, Wr, Ybuf, Rbuf, N);
    k_aggregate<<<nbNode, 256, 0, stream>>>(Ybuf, Rbuf, Hbuf, rowptr, esrc, bl, Hbuf, N, 1);

    // layer 2
    k_gemm_dual<<<nbGemm, 256, 0, stream>>>(Hbuf, HID, HID, Wl + HID * HID, Wr + HID * HID,
                                            Ybuf, Rbuf, N);
    k_aggregate<<<nbNode, 256, 0, stream>>>(Ybuf, Rbuf, Hbuf, rowptr, esrc, bl + HID, Hbuf, N, 1);

    // final linear
    k_final<<<nbNode, 256, 0, stream>>>(Hbuf, lW, lb, out, N);
}

// Round 2
// 986.140 us; speedup vs baseline: 3.1080x; 3.1080x over previous
//
#include <hip/hip_runtime.h>
#include <hip/hip_bf16.h>

#define N_NODES 100000
#define N_EDGES 1600000
#define F_IN 165
#define KP0 192   // F_IN padded to multiple of 32
#define HID 128

typedef __attribute__((ext_vector_type(8))) short bf16x8;
typedef __attribute__((ext_vector_type(4))) float f32x4;

__device__ __forceinline__ short f2bf(float f) {
    unsigned u = __float_as_uint(f);
    unsigned r = (u + 0x7fffu + ((u >> 16) & 1u)) >> 16;  // RNE
    return (short)r;
}

// ---------------- CSR build ----------------

__global__ __launch_bounds__(256) void k_hist(const int* __restrict__ dst, int E, int* __restrict__ cnt) {
    int e = blockIdx.x * 256 + threadIdx.x;
    if (e < E) atomicAdd(&cnt[dst[e]], 1);
}

__global__ __launch_bounds__(512) void k_scan1(const int* __restrict__ deg, int* __restrict__ rowptr,
                                               int* __restrict__ bsum, int N) {
    __shared__ int tmp[512];
    int t = threadIdx.x;
    int i = blockIdx.x * 512 + t;
    int v = (i < N) ? deg[i] : 0;
    tmp[t] = v;
    __syncthreads();
    for (int off = 1; off < 512; off <<= 1) {
        int x = (t >= off) ? tmp[t - off] : 0;
        __syncthreads();
        tmp[t] += x;
        __syncthreads();
    }
    if (i < N) rowptr[i] = tmp[t] - v;
    if (t == 511) bsum[blockIdx.x] = tmp[511];
}

__global__ __launch_bounds__(256) void k_scan2(const int* __restrict__ bsum, int* __restrict__ boff, int nb) {
    __shared__ int tmp[256];
    int t = threadIdx.x;
    int v = (t < nb) ? bsum[t] : 0;
    tmp[t] = v;
    __syncthreads();
    for (int off = 1; off < 256; off <<= 1) {
        int x = (t >= off) ? tmp[t - off] : 0;
        __syncthreads();
        tmp[t] += x;
        __syncthreads();
    }
    if (t < nb) boff[t] = tmp[t] - v;
}

__global__ __launch_bounds__(512) void k_scan3(int* __restrict__ rowptr, const int* __restrict__ boff,
                                               int* __restrict__ cursor, int N, int E) {
    int i = blockIdx.x * 512 + threadIdx.x;
    if (i < N) {
        int v = rowptr[i] + boff[blockIdx.x];
        rowptr[i] = v;
        cursor[i] = v;
    }
    if (i == 0) rowptr[N] = E;
}

__global__ __launch_bounds__(256) void k_scatter(const int* __restrict__ src, const int* __restrict__ dst,
                                                 int* __restrict__ cursor, int* __restrict__ esrc, int E) {
    int e = blockIdx.x * 256 + threadIdx.x;
    if (e < E) {
        int pos = atomicAdd(&cursor[dst[e]], 1);
        esrc[pos] = src[e];
    }
}

// ---------------- casts ----------------

// x [N,165] f32 -> xb [N+pad, 192] bf16 (zero-padded cols)
__global__ __launch_bounds__(256) void k_cast_x(const float* __restrict__ x, short* __restrict__ xb, int N) {
    long long idx = (long long)blockIdx.x * 256 + threadIdx.x;
    long long total = (long long)N * KP0;
    if (idx >= total) return;
    int row = (int)(idx / KP0), col = (int)(idx % KP0);
    float v = (col < F_IN) ? x[(size_t)row * F_IN + col] : 0.f;
    xb[idx] = f2bf(v);
}

// Wl0/Wr0 [128,165] -> Wb0 [256,192]
__global__ __launch_bounds__(256) void k_cast_w0(const float* __restrict__ Wl, const float* __restrict__ Wr,
                                                 short* __restrict__ Wb) {
    int idx = blockIdx.x * 256 + threadIdx.x;
    if (idx >= 256 * KP0) return;
    int row = idx / KP0, col = idx % KP0;
    const float* W = (row < 128) ? Wl : Wr;
    float v = (col < F_IN) ? W[(size_t)(row & 127) * F_IN + col] : 0.f;
    Wb[idx] = f2bf(v);
}

// Wl/Wr [2,128,128] -> Wb12 [2,256,128]
__global__ __launch_bounds__(256) void k_cast_w12(const float* __restrict__ Wl, const float* __restrict__ Wr,
                                                  short* __restrict__ Wb) {
    int idx = blockIdx.x * 256 + threadIdx.x;
    if (idx >= 2 * 256 * HID) return;
    int layer = idx / (256 * HID);
    int rem = idx % (256 * HID);
    int row = rem / HID, col = rem % HID;
    const float* W = (row < 128) ? Wl : Wr;
    float v = W[(size_t)layer * HID * HID + (size_t)(row & 127) * HID + col];
    Wb[idx] = f2bf(v);
}

// ---------------- MFMA dual GEMM ----------------
// A bf16 [M(+pad)][KP], W bf16 [256][KP]; Y = A@W[0:128].T, R = A@W[128:256].T (f32)
// block = 256 thr = 4 waves; wave handles 16 rows x 256 cols.
template <int KPV>
__global__ __launch_bounds__(256) void k_gemm_mfma(
    const short* __restrict__ A, const short* __restrict__ W,
    float* __restrict__ Y, float* __restrict__ R, int M)
{
    constexpr int NK = KPV / 32;
    int wave = threadIdx.x >> 6;
    int lane = threadIdx.x & 63;
    int m0 = blockIdx.x * 64 + wave * 16;
    int lr = lane & 15;   // A row / W row (output col) within tile
    int kg = lane >> 4;   // k-group: k = kg*8 .. +7

    bf16x8 a[NK];
    const short* arow = A + (size_t)(m0 + lr) * KPV + kg * 8;
#pragma unroll
    for (int ks = 0; ks < NK; ks++)
        a[ks] = *(const bf16x8*)(arow + ks * 32);

#pragma unroll
    for (int nt = 0; nt < 16; nt++) {
        f32x4 acc = {0.f, 0.f, 0.f, 0.f};
        const short* wrow = W + (size_t)(nt * 16 + lr) * KPV + kg * 8;
#pragma unroll
        for (int ks = 0; ks < NK; ks++) {
            bf16x8 b = *(const bf16x8*)(wrow + ks * 32);
            acc = __builtin_amdgcn_mfma_f32_16x16x32_bf16(a[ks], b, acc, 0, 0, 0);
        }
        int col = nt * 16 + lr;            // D col = lane&15
        float* dst = (col < HID) ? Y : R;
        int c = col & (HID - 1);
#pragma unroll
        for (int r = 0; r < 4; r++) {
            int node = m0 + kg * 4 + r;    // D row = (lane>>4)*4 + r
            if (node < M) dst[(size_t)node * HID + c] = acc[r];
        }
    }
}

// ---------------- fused aggregate + bias + root + (LN) + ReLU ----------------
__global__ __launch_bounds__(256) void k_aggregate(
    const float* __restrict__ Y, const float* __restrict__ Rm,
    const float* __restrict__ Hres,
    const int* __restrict__ rowptr, const int* __restrict__ esrc,
    const float* __restrict__ bias, float* __restrict__ Hout,
    short* __restrict__ HbOut,   // bf16 copy for next layer's GEMM (may be null)
    int N, int mode)
{
    int lane = threadIdx.x & 63;
    int node = blockIdx.x * 4 + (threadIdx.x >> 6);
    if (node >= N) return;
    int beg = rowptr[node], end = rowptr[node + 1];
    float s0 = 0.f, s1 = 0.f;
    for (int j = beg; j < end; ++j) {
        int s = esrc[j];
        const float* yr = Y + (size_t)s * HID;
        s0 += yr[lane];
        s1 += yr[lane + 64];
    }
    float inv = 1.0f / fmaxf((float)(end - beg), 1.0f);
    size_t base = (size_t)node * HID;
    float v0 = s0 * inv + bias[lane]      + Rm[base + lane];
    float v1 = s1 * inv + bias[lane + 64] + Rm[base + lane + 64];
    float o0, o1;
    if (mode == 0) {
        o0 = fmaxf(v0, 0.f);
        o1 = fmaxf(v1, 0.f);
    } else {
        float z0 = v0 + Hres[base + lane];
        float z1 = v1 + Hres[base + lane + 64];
        float sum = z0 + z1;
#pragma unroll
        for (int off = 32; off; off >>= 1) sum += __shfl_xor(sum, off);
        float mu = sum * (1.f / 128.f);
        float d0 = z0 - mu, d1 = z1 - mu;
        float vs = d0 * d0 + d1 * d1;
#pragma unroll
        for (int off = 32; off; off >>= 1) vs += __shfl_xor(vs, off);
        float rstd = rsqrtf(vs * (1.f / 128.f) + 1e-5f);
        o0 = fmaxf(d0 * rstd, 0.f);
        o1 = fmaxf(d1 * rstd, 0.f);
    }
    Hout[base + lane]      = o0;
    Hout[base + lane + 64] = o1;
    if (HbOut) {
        HbOut[base + lane]      = f2bf(o0);
        HbOut[base + lane + 64] = f2bf(o1);
    }
}

// ---------------- final linear 128 -> 2 ----------------
__global__ __launch_bounds__(256) void k_final(
    const float* __restrict__ Hf, const float* __restrict__ linW,
    const float* __restrict__ linb, float* __restrict__ out, int N)
{
    int lane = threadIdx.x & 63;
    int node = blockIdx.x * 4 + (threadIdx.x >> 6);
    if (node >= N) return;
    size_t base = (size_t)node * HID;
    float h0 = Hf[base + lane], h1 = Hf[base + lane + 64];
    float p0 = h0 * linW[lane]       + h1 * linW[lane + 64];
    float p1 = h0 * linW[128 + lane] + h1 * linW[128 + lane + 64];
#pragma unroll
    for (int off = 32; off; off >>= 1) {
        p0 += __shfl_xor(p0, off);
        p1 += __shfl_xor(p1, off);
    }
    if (lane == 0) {
        out[(size_t)node * 2 + 0] = p0 + linb[0];
        out[(size_t)node * 2 + 1] = p1 + linb[1];
    }
}

extern "C" void kernel_launch(void* const* d_in, const int* in_sizes, int n_in,
                              void* d_out, int out_size, void* d_ws, size_t ws_size,
                              hipStream_t stream) {
    const int N = N_NODES, E = N_EDGES;
    const float* x   = (const float*)d_in[0];
    const int*   ei  = (const int*)d_in[1];
    const float* Wl0 = (const float*)d_in[2];
    const float* bl0 = (const float*)d_in[3];
    const float* Wr0 = (const float*)d_in[4];
    const float* Wl  = (const float*)d_in[5];
    const float* bl  = (const float*)d_in[6];
    const float* Wr  = (const float*)d_in[7];
    const float* lW  = (const float*)d_in[8];
    const float* lb  = (const float*)d_in[9];
    float* out = (float*)d_out;

    const int* src = ei;
    const int* dst = ei + E;

    const int PADR = 64;  // extra rows so MFMA fragment loads past M stay in-bounds

    char* w = (char*)d_ws;
    float* Hbuf = (float*)w; w += (size_t)N * HID * sizeof(float);
    float* Ybuf = (float*)w; w += (size_t)N * HID * sizeof(float);
    float* Rbuf = (float*)w; w += (size_t)N * HID * sizeof(float);
    short* Hb   = (short*)w; w += (size_t)(N + PADR) * HID * sizeof(short);
    short* xb   = (short*)w; w += (size_t)(N + PADR) * KP0 * sizeof(short);
    short* Wb0  = (short*)w; w += (size_t)256 * KP0 * sizeof(short);
    short* Wb12 = (short*)w; w += (size_t)2 * 256 * HID * sizeof(short);
    int* cursor = (int*)w;   w += (size_t)N * sizeof(int);
    int* rowptr = (int*)w;   w += (size_t)(N + 1) * sizeof(int);
    int* bsum   = (int*)w;   w += 256 * sizeof(int);
    int* boff   = (int*)w;   w += 256 * sizeof(int);
    int* esrc   = (int*)w;   w += (size_t)E * sizeof(int);

    const int nbScan = (N + 511) / 512;
    const int nbE    = (E + 255) / 256;
    const int nbGemm = (N + 63) / 64;
    const int nbNode = (N + 3) / 4;

    // CSR build
    hipMemsetAsync(cursor, 0, (size_t)N * sizeof(int), stream);
    k_hist<<<nbE, 256, 0, stream>>>(dst, E, cursor);
    k_scan1<<<nbScan, 512, 0, stream>>>(cursor, rowptr, bsum, N);
    k_scan2<<<1, 256, 0, stream>>>(bsum, boff, nbScan);
    k_scan3<<<nbScan, 512, 0, stream>>>(rowptr, boff, cursor, N, E);
    k_scatter<<<nbE, 256, 0, stream>>>(src, dst, cursor, esrc, E);

    // casts
    {
        long long tot = (long long)N * KP0;
        k_cast_x<<<(int)((tot + 255) / 256), 256, 0, stream>>>(x, xb, N);
        k_cast_w0<<<(256 * KP0 + 255) / 256, 256, 0, stream>>>(Wl0, Wr0, Wb0);
        k_cast_w12<<<(2 * 256 * HID + 255) / 256, 256, 0, stream>>>(Wl, Wr, Wb12);
    }

    // layer 0
    k_gemm_mfma<KP0><<<nbGemm, 256, 0, stream>>>(xb, Wb0, Ybuf, Rbuf, N);
    k_aggregate<<<nbNode, 256, 0, stream>>>(Ybuf, Rbuf, nullptr, rowptr, esrc, bl0, Hbuf, Hb, N, 0);

    // layer 1
    k_gemm_mfma<HID><<<nbGemm, 256, 0, stream>>>(Hb, Wb12, Ybuf, Rbuf, N);
    k_aggregate<<<nbNode, 256, 0, stream>>>(Ybuf, Rbuf, Hbuf, rowptr, esrc, bl, Hbuf, Hb, N, 1);

    // layer 2
    k_gemm_mfma<HID><<<nbGemm, 256, 0, stream>>>(Hb, Wb12 + 256 * HID, Ybuf, Rbuf, N);
    k_aggregate<<<nbNode, 256, 0, stream>>>(Ybuf, Rbuf, Hbuf, rowptr, esrc, bl + HID, Hbuf, nullptr, N, 1);

    // final
    k_final<<<nbNode, 256, 0, stream>>>(Hbuf, lW, lb, out, N);
}

// Round 3
// 684.557 us; speedup vs baseline: 4.4772x; 1.4406x over previous
//
#include <hip/hip_runtime.h>
#include <hip/hip_bf16.h>

#define N_NODES 100000
#define N_EDGES 1600000
#define F_IN 165
#define KP0 192   // F_IN padded to multiple of 32
#define HID 128

typedef __attribute__((ext_vector_type(8))) short bf16x8;
typedef __attribute__((ext_vector_type(4))) float f32x4;

__device__ __forceinline__ ushort f2bf(float f) {
    unsigned u = __float_as_uint(f);
    unsigned r = (u + 0x7fffu + ((u >> 16) & 1u)) >> 16;  // RNE
    return (ushort)r;
}
__device__ __forceinline__ float bflo(unsigned p) { return __uint_as_float(p << 16); }
__device__ __forceinline__ float bfhi(unsigned p) { return __uint_as_float(p & 0xffff0000u); }

// ---------------- CSR build ----------------

__global__ __launch_bounds__(256) void k_hist(const int* __restrict__ dst, int E, int* __restrict__ cnt) {
    int e = blockIdx.x * 256 + threadIdx.x;
    if (e < E) atomicAdd(&cnt[dst[e]], 1);
}

__global__ __launch_bounds__(512) void k_scan1(const int* __restrict__ deg, int* __restrict__ rowptr,
                                               int* __restrict__ bsum, int N) {
    __shared__ int tmp[512];
    int t = threadIdx.x;
    int i = blockIdx.x * 512 + t;
    int v = (i < N) ? deg[i] : 0;
    tmp[t] = v;
    __syncthreads();
    for (int off = 1; off < 512; off <<= 1) {
        int x = (t >= off) ? tmp[t - off] : 0;
        __syncthreads();
        tmp[t] += x;
        __syncthreads();
    }
    if (i < N) rowptr[i] = tmp[t] - v;
    if (t == 511) bsum[blockIdx.x] = tmp[511];
}

__global__ __launch_bounds__(256) void k_scan2(const int* __restrict__ bsum, int* __restrict__ boff, int nb) {
    __shared__ int tmp[256];
    int t = threadIdx.x;
    int v = (t < nb) ? bsum[t] : 0;
    tmp[t] = v;
    __syncthreads();
    for (int off = 1; off < 256; off <<= 1) {
        int x = (t >= off) ? tmp[t - off] : 0;
        __syncthreads();
        tmp[t] += x;
        __syncthreads();
    }
    if (t < nb) boff[t] = tmp[t] - v;
}

__global__ __launch_bounds__(512) void k_scan3(int* __restrict__ rowptr, const int* __restrict__ boff,
                                               int* __restrict__ cursor, int N, int E) {
    int i = blockIdx.x * 512 + threadIdx.x;
    if (i < N) {
        int v = rowptr[i] + boff[blockIdx.x];
        rowptr[i] = v;
        cursor[i] = v;
    }
    if (i == 0) rowptr[N] = E;
}

__global__ __launch_bounds__(256) void k_scatter(const int* __restrict__ src, const int* __restrict__ dst,
                                                 int* __restrict__ cursor, int* __restrict__ esrc, int E) {
    int e = blockIdx.x * 256 + threadIdx.x;
    if (e < E) {
        int pos = atomicAdd(&cursor[dst[e]], 1);
        esrc[pos] = src[e];
    }
}

// ---------------- casts ----------------

__global__ __launch_bounds__(256) void k_cast_x(const float* __restrict__ x, short* __restrict__ xb, int N) {
    long long idx = (long long)blockIdx.x * 256 + threadIdx.x;
    long long total = (long long)N * KP0;
    if (idx >= total) return;
    int row = (int)(idx / KP0), col = (int)(idx % KP0);
    float v = (col < F_IN) ? x[(size_t)row * F_IN + col] : 0.f;
    xb[idx] = (short)f2bf(v);
}

__global__ __launch_bounds__(256) void k_cast_w0(const float* __restrict__ Wl, const float* __restrict__ Wr,
                                                 short* __restrict__ Wb) {
    int idx = blockIdx.x * 256 + threadIdx.x;
    if (idx >= 256 * KP0) return;
    int row = idx / KP0, col = idx % KP0;
    const float* W = (row < 128) ? Wl : Wr;
    float v = (col < F_IN) ? W[(size_t)(row & 127) * F_IN + col] : 0.f;
    Wb[idx] = (short)f2bf(v);
}

__global__ __launch_bounds__(256) void k_cast_w12(const float* __restrict__ Wl, const float* __restrict__ Wr,
                                                  short* __restrict__ Wb) {
    int idx = blockIdx.x * 256 + threadIdx.x;
    if (idx >= 2 * 256 * HID) return;
    int layer = idx / (256 * HID);
    int rem = idx % (256 * HID);
    int row = rem / HID, col = rem % HID;
    const float* W = (row < 128) ? Wl : Wr;
    float v = W[(size_t)layer * HID * HID + (size_t)(row & 127) * HID + col];
    Wb[idx] = (short)f2bf(v);
}

// ---------------- MFMA dual GEMM ----------------
// A bf16 [M+pad][KPV], W bf16 [256][KPV]; Yb = bf16(A@W[0:128].T), R = f32(A@W[128:256].T)
template <int KPV>
__global__ __launch_bounds__(256) void k_gemm_mfma(
    const short* __restrict__ A, const short* __restrict__ W,
    ushort* __restrict__ Yb, float* __restrict__ R, int M)
{
    constexpr int NK = KPV / 32;
    int wave = threadIdx.x >> 6;
    int lane = threadIdx.x & 63;
    int m0 = blockIdx.x * 64 + wave * 16;
    int lr = lane & 15;
    int kg = lane >> 4;

    bf16x8 a[NK];
    const short* arow = A + (size_t)(m0 + lr) * KPV + kg * 8;
#pragma unroll
    for (int ks = 0; ks < NK; ks++)
        a[ks] = *(const bf16x8*)(arow + ks * 32);

#pragma unroll
    for (int nt = 0; nt < 16; nt++) {
        f32x4 acc = {0.f, 0.f, 0.f, 0.f};
        const short* wrow = W + (size_t)(nt * 16 + lr) * KPV + kg * 8;
#pragma unroll
        for (int ks = 0; ks < NK; ks++) {
            bf16x8 b = *(const bf16x8*)(wrow + ks * 32);
            acc = __builtin_amdgcn_mfma_f32_16x16x32_bf16(a[ks], b, acc, 0, 0, 0);
        }
        int c = nt * 16 + lr;  // output feature; nt<8 -> Y half, else R half (uniform per nt)
#pragma unroll
        for (int r = 0; r < 4; r++) {
            int node = m0 + kg * 4 + r;
            if (node >= M) continue;
            if (nt < 8) Yb[(size_t)node * HID + c] = f2bf(acc[r]);
            else        R[(size_t)node * HID + (c - HID)] = acc[r];
        }
    }
}

// ---------------- fused aggregate + bias + root + (LN) + ReLU (+ final proj) ----------------
// one wave per node; lane owns features 2*lane, 2*lane+1
// mode 0: relu -> Hb ; mode 1: residual+LN+relu -> Hb ; mode 2: residual+LN+relu -> out proj
__global__ __launch_bounds__(256) void k_aggregate(
    const ushort* __restrict__ Yb, const float* __restrict__ Rm,
    const ushort* __restrict__ Hres,
    const int* __restrict__ rowptr, const int* __restrict__ esrc,
    const float* __restrict__ bias, ushort* __restrict__ HbOut,
    const float* __restrict__ lW, const float* __restrict__ lb,
    float* __restrict__ out, int N, int mode)
{
    int lane = threadIdx.x & 63;
    int node = blockIdx.x * 4 + (threadIdx.x >> 6);
    if (node >= N) return;
    int beg = rowptr[node], end = rowptr[node + 1];
    float s0 = 0.f, s1 = 0.f;
    for (int c0 = beg; c0 < end; c0 += 64) {
        int cnt = end - c0; if (cnt > 64) cnt = 64;
        int ids = (c0 + lane < end) ? esrc[c0 + lane] : 0;
        int t = 0;
        for (; t + 1 < cnt; t += 2) {
            int sa = __shfl(ids, t);
            int sb = __shfl(ids, t + 1);
            unsigned pa = *(const unsigned*)(Yb + (size_t)sa * HID + lane * 2);
            unsigned pb = *(const unsigned*)(Yb + (size_t)sb * HID + lane * 2);
            s0 += bflo(pa) + bflo(pb);
            s1 += bfhi(pa) + bfhi(pb);
        }
        if (t < cnt) {
            int sa = __shfl(ids, t);
            unsigned pa = *(const unsigned*)(Yb + (size_t)sa * HID + lane * 2);
            s0 += bflo(pa);
            s1 += bfhi(pa);
        }
    }
    float inv = 1.0f / fmaxf((float)(end - beg), 1.0f);
    size_t base = (size_t)node * HID;
    float2 b2 = *(const float2*)(bias + 2 * lane);
    float2 r2 = *(const float2*)(Rm + base + 2 * lane);
    float v0 = s0 * inv + b2.x + r2.x;
    float v1 = s1 * inv + b2.y + r2.y;
    float o0, o1;
    if (mode == 0) {
        o0 = fmaxf(v0, 0.f);
        o1 = fmaxf(v1, 0.f);
    } else {
        unsigned h2 = *(const unsigned*)(Hres + base + 2 * lane);
        float z0 = v0 + bflo(h2);
        float z1 = v1 + bfhi(h2);
        float sum = z0 + z1;
#pragma unroll
        for (int off = 32; off; off >>= 1) sum += __shfl_xor(sum, off);
        float mu = sum * (1.f / 128.f);
        float d0 = z0 - mu, d1 = z1 - mu;
        float vs = d0 * d0 + d1 * d1;
#pragma unroll
        for (int off = 32; off; off >>= 1) vs += __shfl_xor(vs, off);
        float rstd = rsqrtf(vs * (1.f / 128.f) + 1e-5f);
        o0 = fmaxf(d0 * rstd, 0.f);
        o1 = fmaxf(d1 * rstd, 0.f);
    }
    if (mode == 2) {
        float2 w0 = *(const float2*)(lW + 2 * lane);
        float2 w1 = *(const float2*)(lW + 128 + 2 * lane);
        float p0 = o0 * w0.x + o1 * w0.y;
        float p1 = o0 * w1.x + o1 * w1.y;
#pragma unroll
        for (int off = 32; off; off >>= 1) {
            p0 += __shfl_xor(p0, off);
            p1 += __shfl_xor(p1, off);
        }
        if (lane == 0) {
            out[(size_t)node * 2 + 0] = p0 + lb[0];
            out[(size_t)node * 2 + 1] = p1 + lb[1];
        }
    } else {
        unsigned pk = (unsigned)f2bf(o0) | ((unsigned)f2bf(o1) << 16);
        *(unsigned*)(HbOut + base + 2 * lane) = pk;
    }
}

extern "C" void kernel_launch(void* const* d_in, const int* in_sizes, int n_in,
                              void* d_out, int out_size, void* d_ws, size_t ws_size,
                              hipStream_t stream) {
    const int N = N_NODES, E = N_EDGES;
    const float* x   = (const float*)d_in[0];
    const int*   ei  = (const int*)d_in[1];
    const float* Wl0 = (const float*)d_in[2];
    const float* bl0 = (const float*)d_in[3];
    const float* Wr0 = (const float*)d_in[4];
    const float* Wl  = (const float*)d_in[5];
    const float* bl  = (const float*)d_in[6];
    const float* Wr  = (const float*)d_in[7];
    const float* lW  = (const float*)d_in[8];
    const float* lb  = (const float*)d_in[9];
    float* out = (float*)d_out;

    const int* src = ei;
    const int* dst = ei + E;

    const int PADR = 64;

    char* w = (char*)d_ws;
    ushort* Yb  = (ushort*)w; w += (size_t)(N + PADR) * HID * sizeof(ushort);
    float*  R   = (float*)w;  w += (size_t)N * HID * sizeof(float);
    ushort* Hb  = (ushort*)w; w += (size_t)(N + PADR) * HID * sizeof(ushort);
    short*  xb  = (short*)w;  w += (size_t)(N + PADR) * KP0 * sizeof(short);
    short*  Wb0 = (short*)w;  w += (size_t)256 * KP0 * sizeof(short);
    short*  Wb12= (short*)w;  w += (size_t)2 * 256 * HID * sizeof(short);
    int* cursor = (int*)w;    w += (size_t)N * sizeof(int);
    int* rowptr = (int*)w;    w += (size_t)(N + 1) * sizeof(int);
    int* bsum   = (int*)w;    w += 256 * sizeof(int);
    int* boff   = (int*)w;    w += 256 * sizeof(int);
    int* esrc   = (int*)w;    w += (size_t)E * sizeof(int);

    const int nbScan = (N + 511) / 512;
    const int nbE    = (E + 255) / 256;
    const int nbGemm = (N + 63) / 64;
    const int nbNode = (N + 3) / 4;

    // CSR build
    hipMemsetAsync(cursor, 0, (size_t)N * sizeof(int), stream);
    k_hist<<<nbE, 256, 0, stream>>>(dst, E, cursor);
    k_scan1<<<nbScan, 512, 0, stream>>>(cursor, rowptr, bsum, N);
    k_scan2<<<1, 256, 0, stream>>>(bsum, boff, nbScan);
    k_scan3<<<nbScan, 512, 0, stream>>>(rowptr, boff, cursor, N, E);
    k_scatter<<<nbE, 256, 0, stream>>>(src, dst, cursor, esrc, E);

    // casts
    {
        long long tot = (long long)N * KP0;
        k_cast_x<<<(int)((tot + 255) / 256), 256, 0, stream>>>(x, xb, N);
        k_cast_w0<<<(256 * KP0 + 255) / 256, 256, 0, stream>>>(Wl0, Wr0, Wb0);
        k_cast_w12<<<(2 * 256 * HID + 255) / 256, 256, 0, stream>>>(Wl, Wr, Wb12);
    }

    // layer 0
    k_gemm_mfma<KP0><<<nbGemm, 256, 0, stream>>>(xb, Wb0, Yb, R, N);
    k_aggregate<<<nbNode, 256, 0, stream>>>(Yb, R, nullptr, rowptr, esrc, bl0, Hb,
                                            nullptr, nullptr, nullptr, N, 0);

    // layer 1 (residual = Hb, updated in place per node)
    k_gemm_mfma<HID><<<nbGemm, 256, 0, stream>>>((const short*)Hb, Wb12, Yb, R, N);
    k_aggregate<<<nbNode, 256, 0, stream>>>(Yb, R, Hb, rowptr, esrc, bl, Hb,
                                            nullptr, nullptr, nullptr, N, 1);

    // layer 2 + fused final projection
    k_gemm_mfma<HID><<<nbGemm, 256, 0, stream>>>((const short*)Hb, Wb12 + 256 * HID, Yb, R, N);
    k_aggregate<<<nbNode, 256, 0, stream>>>(Yb, R, Hb, rowptr, esrc, bl + HID, nullptr,
                                            lW, lb, out, N, 2);
}

// Round 4
// 537.239 us; speedup vs baseline: 5.7050x; 1.2742x over previous
//
#include <hip/hip_runtime.h>
#include <hip/hip_bf16.h>

#define N_NODES 100000
#define N_EDGES 1600000
#define F_IN 165
#define KP0 192   // F_IN padded to multiple of 32
#define HID 128

#define NBKT 196   // ceil(N/512) coarse buckets (dst>>9)
#define EPB1 8192  // edges per block in coarse passes
#define NBLK1 196  // ceil(E/EPB1)

typedef __attribute__((ext_vector_type(8))) short bf16x8;
typedef __attribute__((ext_vector_type(4))) float f32x4;

__device__ __forceinline__ ushort f2bf(float f) {
    unsigned u = __float_as_uint(f);
    unsigned r = (u + 0x7fffu + ((u >> 16) & 1u)) >> 16;  // RNE
    return (ushort)r;
}
__device__ __forceinline__ float bflo(unsigned p) { return __uint_as_float(p << 16); }
__device__ __forceinline__ float bfhi(unsigned p) { return __uint_as_float(p & 0xffff0000u); }

// ---------------- CSR build via 2-level counting sort ----------------

// pass 1: per-block coarse histogram (LDS atomics only)
__global__ __launch_bounds__(256) void k_p1(const int* __restrict__ dst, int* __restrict__ counts, int E) {
    __shared__ int h[NBKT];
    int t = threadIdx.x;
    for (int i = t; i < NBKT; i += 256) h[i] = 0;
    __syncthreads();
    int base = blockIdx.x * EPB1;
    for (int i = 0; i < EPB1; i += 256) {
        int e = base + i + t;
        if (e < E) atomicAdd(&h[dst[e] >> 9], 1);
    }
    __syncthreads();
    for (int i = t; i < NBKT; i += 256) counts[blockIdx.x * NBKT + i] = h[i];
}

// pass 2: bucket bases + per-(block,bucket) running offsets
__global__ __launch_bounds__(256) void k_p2(const int* __restrict__ counts, int* __restrict__ offs,
                                            int* __restrict__ bbase, int* __restrict__ rowptr, int E) {
    __shared__ int s[256];
    int t = threadIdx.x;
    int tot = 0;
    if (t < NBKT) {
        for (int blk = 0; blk < NBLK1; blk++) tot += counts[blk * NBKT + t];
    }
    s[t] = (t < NBKT) ? tot : 0;
    __syncthreads();
    for (int off = 1; off < 256; off <<= 1) {
        int v = (t >= off) ? s[t - off] : 0;
        __syncthreads();
        s[t] += v;
        __syncthreads();
    }
    int base = s[t] - tot;  // exclusive
    if (t < NBKT) {
        bbase[t] = base;
        int run = base;
        for (int blk = 0; blk < NBLK1; blk++) {
            int c = counts[blk * NBKT + t];
            offs[blk * NBKT + t] = run;
            run += c;
        }
    }
    if (t == 0) rowptr[N_NODES] = E;
}

// pass 3: coarse scatter of packed (dst_low9<<17 | src) with LDS cursors
__global__ __launch_bounds__(256) void k_p3(const int* __restrict__ src, const int* __restrict__ dst,
                                            const int* __restrict__ offs, int* __restrict__ ebuf, int E) {
    __shared__ int cur[NBKT];
    int t = threadIdx.x;
    for (int i = t; i < NBKT; i += 256) cur[i] = offs[blockIdx.x * NBKT + i];
    __syncthreads();
    int base = blockIdx.x * EPB1;
    for (int i = 0; i < EPB1; i += 256) {
        int e = base + i + t;
        if (e < E) {
            int d = dst[e], s = src[e];
            int b = d >> 9;
            int pos = atomicAdd(&cur[b], 1);
            ebuf[pos] = s | ((d & 511) << 17);
        }
    }
}

// pass 4: fine sort within each bucket -> rowptr + esrc
__global__ __launch_bounds__(256) void k_p4(const int* __restrict__ ebuf, const int* __restrict__ bbase,
                                            int* __restrict__ rowptr, int* __restrict__ esrc, int E, int N) {
    __shared__ int fh[512], fex[512], fcur[512];
    __shared__ int sc[256];
    int t = threadIdx.x;
    int b = blockIdx.x;
    int base = bbase[b];
    int end = (b + 1 < NBKT) ? bbase[b + 1] : E;
    int cnt = end - base;
    fh[t] = 0; fh[t + 256] = 0; fcur[t] = 0; fcur[t + 256] = 0;
    __syncthreads();
    for (int i = t; i < cnt; i += 256) atomicAdd(&fh[(ebuf[base + i] >> 17) & 511], 1);
    __syncthreads();
    int a0 = fh[2 * t], a1 = fh[2 * t + 1];
    sc[t] = a0 + a1;
    __syncthreads();
    for (int off = 1; off < 256; off <<= 1) {
        int v = (t >= off) ? sc[t - off] : 0;
        __syncthreads();
        sc[t] += v;
        __syncthreads();
    }
    int ex = sc[t] - (a0 + a1);
    fex[2 * t] = ex;
    fex[2 * t + 1] = ex + a0;
    __syncthreads();
    int node0 = b << 9;
    for (int f = t; f < 512; f += 256) {
        int node = node0 + f;
        if (node < N) rowptr[node] = base + fex[f];
    }
    for (int i = t; i < cnt; i += 256) {
        int p = ebuf[base + i];
        int f = (p >> 17) & 511;
        int pos = base + fex[f] + atomicAdd(&fcur[f], 1);
        esrc[pos] = p & 0x1ffff;
    }
}

// ---------------- casts ----------------

__global__ __launch_bounds__(256) void k_cast_x(const float* __restrict__ x, short* __restrict__ xb, int N) {
    long long idx = (long long)blockIdx.x * 256 + threadIdx.x;
    long long total = (long long)N * KP0;
    if (idx >= total) return;
    int row = (int)(idx / KP0), col = (int)(idx % KP0);
    float v = (col < F_IN) ? x[(size_t)row * F_IN + col] : 0.f;
    xb[idx] = (short)f2bf(v);
}

__global__ __launch_bounds__(256) void k_cast_w0(const float* __restrict__ Wl, const float* __restrict__ Wr,
                                                 short* __restrict__ Wb) {
    int idx = blockIdx.x * 256 + threadIdx.x;
    if (idx >= 256 * KP0) return;
    int row = idx / KP0, col = idx % KP0;
    const float* W = (row < 128) ? Wl : Wr;
    float v = (col < F_IN) ? W[(size_t)(row & 127) * F_IN + col] : 0.f;
    Wb[idx] = (short)f2bf(v);
}

__global__ __launch_bounds__(256) void k_cast_w12(const float* __restrict__ Wl, const float* __restrict__ Wr,
                                                  short* __restrict__ Wb) {
    int idx = blockIdx.x * 256 + threadIdx.x;
    if (idx >= 2 * 256 * HID) return;
    int layer = idx / (256 * HID);
    int rem = idx % (256 * HID);
    int row = rem / HID, col = rem % HID;
    const float* W = (row < 128) ? Wl : Wr;
    float v = W[(size_t)layer * HID * HID + (size_t)(row & 127) * HID + col];
    Wb[idx] = (short)f2bf(v);
}

// ---------------- MFMA dual GEMM ----------------
// A bf16 [M+pad][KPV], W bf16 [256][KPV]; Yb = bf16(A@W[0:128].T), Rb = bf16(A@W[128:256].T)
template <int KPV>
__global__ __launch_bounds__(256) void k_gemm_mfma(
    const short* __restrict__ A, const short* __restrict__ W,
    ushort* __restrict__ Yb, ushort* __restrict__ Rb, int M)
{
    constexpr int NK = KPV / 32;
    int wave = threadIdx.x >> 6;
    int lane = threadIdx.x & 63;
    int m0 = blockIdx.x * 64 + wave * 16;
    int lr = lane & 15;
    int kg = lane >> 4;

    bf16x8 a[NK];
    const short* arow = A + (size_t)(m0 + lr) * KPV + kg * 8;
#pragma unroll
    for (int ks = 0; ks < NK; ks++)
        a[ks] = *(const bf16x8*)(arow + ks * 32);

#pragma unroll
    for (int nt = 0; nt < 16; nt++) {
        f32x4 acc = {0.f, 0.f, 0.f, 0.f};
        const short* wrow = W + (size_t)(nt * 16 + lr) * KPV + kg * 8;
#pragma unroll
        for (int ks = 0; ks < NK; ks++) {
            bf16x8 b = *(const bf16x8*)(wrow + ks * 32);
            acc = __builtin_amdgcn_mfma_f32_16x16x32_bf16(a[ks], b, acc, 0, 0, 0);
        }
        int c = nt * 16 + lr;
#pragma unroll
        for (int r = 0; r < 4; r++) {
            int node = m0 + kg * 4 + r;
            if (node >= M) continue;
            if (nt < 8) Yb[(size_t)node * HID + c] = f2bf(acc[r]);
            else        Rb[(size_t)node * HID + (c - HID)] = f2bf(acc[r]);
        }
    }
}

// ---------------- fused aggregate + bias + root + (LN) + ReLU (+ final proj) ----------------
__global__ __launch_bounds__(256) void k_aggregate(
    const ushort* __restrict__ Yb, const ushort* __restrict__ Rm,
    const ushort* __restrict__ Hres,
    const int* __restrict__ rowptr, const int* __restrict__ esrc,
    const float* __restrict__ bias, ushort* __restrict__ HbOut,
    const float* __restrict__ lW, const float* __restrict__ lb,
    float* __restrict__ out, int N, int mode)
{
    int lane = threadIdx.x & 63;
    int node = blockIdx.x * 4 + (threadIdx.x >> 6);
    if (node >= N) return;
    int beg = rowptr[node], end = rowptr[node + 1];
    float s0 = 0.f, s1 = 0.f;
    for (int c0 = beg; c0 < end; c0 += 64) {
        int cnt = end - c0; if (cnt > 64) cnt = 64;
        int ids = (c0 + lane < end) ? esrc[c0 + lane] : 0;
        int t = 0;
        for (; t + 1 < cnt; t += 2) {
            int sa = __shfl(ids, t);
            int sb = __shfl(ids, t + 1);
            unsigned pa = *(const unsigned*)(Yb + (size_t)sa * HID + lane * 2);
            unsigned pb = *(const unsigned*)(Yb + (size_t)sb * HID + lane * 2);
            s0 += bflo(pa) + bflo(pb);
            s1 += bfhi(pa) + bfhi(pb);
        }
        if (t < cnt) {
            int sa = __shfl(ids, t);
            unsigned pa = *(const unsigned*)(Yb + (size_t)sa * HID + lane * 2);
            s0 += bflo(pa);
            s1 += bfhi(pa);
        }
    }
    float inv = 1.0f / fmaxf((float)(end - beg), 1.0f);
    size_t base = (size_t)node * HID;
    float2 b2 = *(const float2*)(bias + 2 * lane);
    unsigned r2 = *(const unsigned*)(Rm + base + 2 * lane);
    float v0 = s0 * inv + b2.x + bflo(r2);
    float v1 = s1 * inv + b2.y + bfhi(r2);
    float o0, o1;
    if (mode == 0) {
        o0 = fmaxf(v0, 0.f);
        o1 = fmaxf(v1, 0.f);
    } else {
        unsigned h2 = *(const unsigned*)(Hres + base + 2 * lane);
        float z0 = v0 + bflo(h2);
        float z1 = v1 + bfhi(h2);
        float sum = z0 + z1;
#pragma unroll
        for (int off = 32; off; off >>= 1) sum += __shfl_xor(sum, off);
        float mu = sum * (1.f / 128.f);
        float d0 = z0 - mu, d1 = z1 - mu;
        float vs = d0 * d0 + d1 * d1;
#pragma unroll
        for (int off = 32; off; off >>= 1) vs += __shfl_xor(vs, off);
        float rstd = rsqrtf(vs * (1.f / 128.f) + 1e-5f);
        o0 = fmaxf(d0 * rstd, 0.f);
        o1 = fmaxf(d1 * rstd, 0.f);
    }
    if (mode == 2) {
        float2 w0 = *(const float2*)(lW + 2 * lane);
        float2 w1 = *(const float2*)(lW + 128 + 2 * lane);
        float p0 = o0 * w0.x + o1 * w0.y;
        float p1 = o0 * w1.x + o1 * w1.y;
#pragma unroll
        for (int off = 32; off; off >>= 1) {
            p0 += __shfl_xor(p0, off);
            p1 += __shfl_xor(p1, off);
        }
        if (lane == 0) {
            out[(size_t)node * 2 + 0] = p0 + lb[0];
            out[(size_t)node * 2 + 1] = p1 + lb[1];
        }
    } else {
        unsigned pk = (unsigned)f2bf(o0) | ((unsigned)f2bf(o1) << 16);
        *(unsigned*)(HbOut + base + 2 * lane) = pk;
    }
}

extern "C" void kernel_launch(void* const* d_in, const int* in_sizes, int n_in,
                              void* d_out, int out_size, void* d_ws, size_t ws_size,
                              hipStream_t stream) {
    const int N = N_NODES, E = N_EDGES;
    const float* x   = (const float*)d_in[0];
    const int*   ei  = (const int*)d_in[1];
    const float* Wl0 = (const float*)d_in[2];
    const float* bl0 = (const float*)d_in[3];
    const float* Wr0 = (const float*)d_in[4];
    const float* Wl  = (const float*)d_in[5];
    const float* bl  = (const float*)d_in[6];
    const float* Wr  = (const float*)d_in[7];
    const float* lW  = (const float*)d_in[8];
    const float* lb  = (const float*)d_in[9];
    float* out = (float*)d_out;

    const int* src = ei;
    const int* dst = ei + E;

    const int PADR = 64;

    char* w = (char*)d_ws;
    ushort* Yb  = (ushort*)w; w += (size_t)(N + PADR) * HID * sizeof(ushort);
    ushort* Rb  = (ushort*)w; w += (size_t)N * HID * sizeof(ushort);
    ushort* Hb  = (ushort*)w; w += (size_t)(N + PADR) * HID * sizeof(ushort);
    short*  xb  = (short*)w;  w += (size_t)(N + PADR) * KP0 * sizeof(short);
    short*  Wb0 = (short*)w;  w += (size_t)256 * KP0 * sizeof(short);
    short*  Wb12= (short*)w;  w += (size_t)2 * 256 * HID * sizeof(short);
    int* counts = (int*)w;    w += (size_t)NBLK1 * NBKT * sizeof(int);
    int* offs   = (int*)w;    w += (size_t)NBLK1 * NBKT * sizeof(int);
    int* bbase  = (int*)w;    w += (size_t)NBKT * sizeof(int);
    int* rowptr = (int*)w;    w += (size_t)(N + 1) * sizeof(int);
    int* ebuf   = (int*)w;    w += (size_t)E * sizeof(int);
    int* esrc   = (int*)w;    w += (size_t)E * sizeof(int);

    const int nbGemm = (N + 63) / 64;
    const int nbNode = (N + 3) / 4;

    // CSR build (2-level counting sort)
    k_p1<<<NBLK1, 256, 0, stream>>>(dst, counts, E);
    k_p2<<<1, 256, 0, stream>>>(counts, offs, bbase, rowptr, E);
    k_p3<<<NBLK1, 256, 0, stream>>>(src, dst, offs, ebuf, E);
    k_p4<<<NBKT, 256, 0, stream>>>(ebuf, bbase, rowptr, esrc, E, N);

    // casts
    {
        long long tot = (long long)N * KP0;
        k_cast_x<<<(int)((tot + 255) / 256), 256, 0, stream>>>(x, xb, N);
        k_cast_w0<<<(256 * KP0 + 255) / 256, 256, 0, stream>>>(Wl0, Wr0, Wb0);
        k_cast_w12<<<(2 * 256 * HID + 255) / 256, 256, 0, stream>>>(Wl, Wr, Wb12);
    }

    // layer 0
    k_gemm_mfma<KP0><<<nbGemm, 256, 0, stream>>>(xb, Wb0, Yb, Rb, N);
    k_aggregate<<<nbNode, 256, 0, stream>>>(Yb, Rb, nullptr, rowptr, esrc, bl0, Hb,
                                            nullptr, nullptr, nullptr, N, 0);

    // layer 1
    k_gemm_mfma<HID><<<nbGemm, 256, 0, stream>>>((const short*)Hb, Wb12, Yb, Rb, N);
    k_aggregate<<<nbNode, 256, 0, stream>>>(Yb, Rb, Hb, rowptr, esrc, bl, Hb,
                                            nullptr, nullptr, nullptr, N, 1);

    // layer 2 + fused final projection
    k_gemm_mfma<HID><<<nbGemm, 256, 0, stream>>>((const short*)Hb, Wb12 + 256 * HID, Yb, Rb, N);
    k_aggregate<<<nbNode, 256, 0, stream>>>(Yb, Rb, Hb, rowptr, esrc, bl + HID, nullptr,
                                            lW, lb, out, N, 2);
}

// Round 5
// 510.258 us; speedup vs baseline: 6.0066x; 1.0529x over previous
//
#include <hip/hip_runtime.h>
#include <hip/hip_bf16.h>

#define N_NODES 100000
#define N_EDGES 1600000
#define F_IN 165
#define KP0 192   // F_IN padded to multiple of 32
#define HID 128

#define NBKT 196   // ceil(N/512) coarse dst buckets (dst>>9)
#define EPB1 8192  // edges per block in coarse passes
#define NBLK1 196  // ceil(E/EPB1)
#define NSB 13     // src buckets (src>>13, 8192-node = 2MB stripes)

typedef __attribute__((ext_vector_type(8))) short bf16x8;
typedef __attribute__((ext_vector_type(4))) float f32x4;

__device__ __forceinline__ ushort f2bf(float f) {
    unsigned u = __float_as_uint(f);
    unsigned r = (u + 0x7fffu + ((u >> 16) & 1u)) >> 16;  // RNE
    return (ushort)r;
}
__device__ __forceinline__ float bflo(unsigned p) { return __uint_as_float(p << 16); }
__device__ __forceinline__ float bfhi(unsigned p) { return __uint_as_float(p & 0xffff0000u); }

// ---------------- src-bucket pre-sort (for gather L2 locality) ----------------

__global__ __launch_bounds__(256) void k_s1(const int* __restrict__ src, int* __restrict__ counts2, int E) {
    __shared__ int h[NSB];
    int t = threadIdx.x;
    if (t < NSB) h[t] = 0;
    __syncthreads();
    int base = blockIdx.x * EPB1;
    for (int i = 0; i < EPB1; i += 256) {
        int e = base + i + t;
        if (e < E) atomicAdd(&h[src[e] >> 13], 1);
    }
    __syncthreads();
    if (t < NSB) counts2[blockIdx.x * NSB + t] = h[t];
}

__global__ __launch_bounds__(64) void k_s2(const int* __restrict__ counts2, int* __restrict__ offs2) {
    __shared__ int tot[NSB], base[NSB];
    int t = threadIdx.x;
    if (t < NSB) {
        int s = 0;
        for (int b = 0; b < NBLK1; b++) s += counts2[b * NSB + t];
        tot[t] = s;
    }
    __syncthreads();
    if (t == 0) {
        int run = 0;
        for (int i = 0; i < NSB; i++) { base[i] = run; run += tot[i]; }
    }
    __syncthreads();
    if (t < NSB) {
        int run = base[t];
        for (int b = 0; b < NBLK1; b++) {
            offs2[b * NSB + t] = run;
            run += counts2[b * NSB + t];
        }
    }
}

__global__ __launch_bounds__(256) void k_s3(const int* __restrict__ src, const int* __restrict__ dst,
                                            const int* __restrict__ offs2, int2* __restrict__ ebuf2, int E) {
    __shared__ int cur[NSB];
    int t = threadIdx.x;
    if (t < NSB) cur[t] = offs2[blockIdx.x * NSB + t];
    __syncthreads();
    int base = blockIdx.x * EPB1;
    for (int i = 0; i < EPB1; i += 256) {
        int e = base + i + t;
        if (e < E) {
            int s = src[e], d = dst[e];
            int pos = atomicAdd(&cur[s >> 13], 1);
            ebuf2[pos] = make_int2(s, d);
        }
    }
}

// ---------------- CSR build via 2-level counting sort (stable over src order) ----------------

__global__ __launch_bounds__(256) void k_p1(const int2* __restrict__ ebuf2, int* __restrict__ counts, int E) {
    __shared__ int h[NBKT];
    int t = threadIdx.x;
    for (int i = t; i < NBKT; i += 256) h[i] = 0;
    __syncthreads();
    int base = blockIdx.x * EPB1;
    for (int i = 0; i < EPB1; i += 256) {
        int e = base + i + t;
        if (e < E) atomicAdd(&h[ebuf2[e].y >> 9], 1);
    }
    __syncthreads();
    for (int i = t; i < NBKT; i += 256) counts[blockIdx.x * NBKT + i] = h[i];
}

__global__ __launch_bounds__(256) void k_p2(const int* __restrict__ counts, int* __restrict__ offs,
                                            int* __restrict__ bbase, int* __restrict__ rowptr, int E) {
    __shared__ int s[256];
    int t = threadIdx.x;
    int tot = 0;
    if (t < NBKT) {
        for (int blk = 0; blk < NBLK1; blk++) tot += counts[blk * NBKT + t];
    }
    s[t] = (t < NBKT) ? tot : 0;
    __syncthreads();
    for (int off = 1; off < 256; off <<= 1) {
        int v = (t >= off) ? s[t - off] : 0;
        __syncthreads();
        s[t] += v;
        __syncthreads();
    }
    int base = s[t] - tot;  // exclusive
    if (t < NBKT) {
        bbase[t] = base;
        int run = base;
        for (int blk = 0; blk < NBLK1; blk++) {
            int c = counts[blk * NBKT + t];
            offs[blk * NBKT + t] = run;
            run += c;
        }
    }
    if (t == 0) rowptr[N_NODES] = E;
}

__global__ __launch_bounds__(256) void k_p3(const int2* __restrict__ ebuf2,
                                            const int* __restrict__ offs, int* __restrict__ ebuf, int E) {
    __shared__ int cur[NBKT];
    int t = threadIdx.x;
    for (int i = t; i < NBKT; i += 256) cur[i] = offs[blockIdx.x * NBKT + i];
    __syncthreads();
    int base = blockIdx.x * EPB1;
    for (int i = 0; i < EPB1; i += 256) {
        int e = base + i + t;
        if (e < E) {
            int2 ed = ebuf2[e];
            int b = ed.y >> 9;
            int pos = atomicAdd(&cur[b], 1);
            ebuf[pos] = ed.x | ((ed.y & 511) << 17);
        }
    }
}

__global__ __launch_bounds__(256) void k_p4(const int* __restrict__ ebuf, const int* __restrict__ bbase,
                                            int* __restrict__ rowptr, int* __restrict__ esrc, int E, int N) {
    __shared__ int fh[512], fex[512], fcur[512];
    __shared__ int sc[256];
    int t = threadIdx.x;
    int b = blockIdx.x;
    int base = bbase[b];
    int end = (b + 1 < NBKT) ? bbase[b + 1] : E;
    int cnt = end - base;
    fh[t] = 0; fh[t + 256] = 0; fcur[t] = 0; fcur[t + 256] = 0;
    __syncthreads();
    for (int i = t; i < cnt; i += 256) atomicAdd(&fh[(ebuf[base + i] >> 17) & 511], 1);
    __syncthreads();
    int a0 = fh[2 * t], a1 = fh[2 * t + 1];
    sc[t] = a0 + a1;
    __syncthreads();
    for (int off = 1; off < 256; off <<= 1) {
        int v = (t >= off) ? sc[t - off] : 0;
        __syncthreads();
        sc[t] += v;
        __syncthreads();
    }
    int ex = sc[t] - (a0 + a1);
    fex[2 * t] = ex;
    fex[2 * t + 1] = ex + a0;
    __syncthreads();
    int node0 = b << 9;
    for (int f = t; f < 512; f += 256) {
        int node = node0 + f;
        if (node < N) rowptr[node] = base + fex[f];
    }
    for (int i = t; i < cnt; i += 256) {
        int p = ebuf[base + i];
        int f = (p >> 17) & 511;
        int pos = base + fex[f] + atomicAdd(&fcur[f], 1);
        esrc[pos] = p & 0x1ffff;
    }
}

// ---------------- weight casts ----------------

__global__ __launch_bounds__(256) void k_cast_w0(const float* __restrict__ Wl, const float* __restrict__ Wr,
                                                 short* __restrict__ Wb) {
    int idx = blockIdx.x * 256 + threadIdx.x;
    if (idx >= 256 * KP0) return;
    int row = idx / KP0, col = idx % KP0;
    const float* W = (row < 128) ? Wl : Wr;
    float v = (col < F_IN) ? W[(size_t)(row & 127) * F_IN + col] : 0.f;
    Wb[idx] = (short)f2bf(v);
}

__global__ __launch_bounds__(256) void k_cast_w12(const float* __restrict__ Wl, const float* __restrict__ Wr,
                                                  short* __restrict__ Wb) {
    int idx = blockIdx.x * 256 + threadIdx.x;
    if (idx >= 2 * 256 * HID) return;
    int layer = idx / (256 * HID);
    int rem = idx % (256 * HID);
    int row = rem / HID, col = rem % HID;
    const float* W = (row < 128) ? Wl : Wr;
    float v = W[(size_t)layer * HID * HID + (size_t)(row & 127) * HID + col];
    Wb[idx] = (short)f2bf(v);
}

// ---------------- MFMA dual GEMM ----------------
// A: f32 [M][KREAL] (AF32) or bf16 [M+pad][KPV]; W bf16 [256][KPV]
// Yb = bf16(A@W[0:128].T), Rb = bf16(A@W[128:256].T)
template <int KPV, int KREAL, bool AF32>
__global__ __launch_bounds__(256) void k_gemm_mfma(
    const void* __restrict__ Av, const short* __restrict__ W,
    ushort* __restrict__ Yb, ushort* __restrict__ Rb, int M)
{
    constexpr int NK = KPV / 32;
    int wave = threadIdx.x >> 6;
    int lane = threadIdx.x & 63;
    int m0 = blockIdx.x * 64 + wave * 16;
    int lr = lane & 15;
    int kg = lane >> 4;

    int row = m0 + lr;
    if (row >= M) row = M - 1;  // clamp: keeps loads in-bounds; stores are guarded

    bf16x8 a[NK];
    if constexpr (AF32) {
        const float* arow = (const float*)Av + (size_t)row * KREAL;
#pragma unroll
        for (int ks = 0; ks < NK; ks++) {
#pragma unroll
            for (int j = 0; j < 8; j++) {
                int k = ks * 32 + kg * 8 + j;
                float v = (k < KREAL) ? arow[k] : 0.f;
                a[ks][j] = (short)f2bf(v);
            }
        }
    } else {
        const short* arow = (const short*)Av + (size_t)row * KPV + kg * 8;
#pragma unroll
        for (int ks = 0; ks < NK; ks++)
            a[ks] = *(const bf16x8*)(arow + ks * 32);
    }

#pragma unroll
    for (int nt = 0; nt < 16; nt++) {
        f32x4 acc = {0.f, 0.f, 0.f, 0.f};
        const short* wrow = W + (size_t)(nt * 16 + lr) * KPV + kg * 8;
#pragma unroll
        for (int ks = 0; ks < NK; ks++) {
            bf16x8 b = *(const bf16x8*)(wrow + ks * 32);
            acc = __builtin_amdgcn_mfma_f32_16x16x32_bf16(a[ks], b, acc, 0, 0, 0);
        }
        int c = nt * 16 + lr;
#pragma unroll
        for (int r = 0; r < 4; r++) {
            int node = m0 + kg * 4 + r;
            if (node >= M) continue;
            if (nt < 8) Yb[(size_t)node * HID + c] = f2bf(acc[r]);
            else        Rb[(size_t)node * HID + (c - HID)] = f2bf(acc[r]);
        }
    }
}

// ---------------- fused aggregate + bias + root + (LN) + ReLU (+ final proj) ----------------
__global__ __launch_bounds__(256) void k_aggregate(
    const ushort* __restrict__ Yb, const ushort* __restrict__ Rm,
    const ushort* __restrict__ Hres,
    const int* __restrict__ rowptr, const int* __restrict__ esrc,
    const float* __restrict__ bias, ushort* __restrict__ HbOut,
    const float* __restrict__ lW, const float* __restrict__ lb,
    float* __restrict__ out, int N, int mode)
{
    int lane = threadIdx.x & 63;
    int node = blockIdx.x * 4 + (threadIdx.x >> 6);
    if (node >= N) return;
    int beg = rowptr[node], end = rowptr[node + 1];
    float s0 = 0.f, s1 = 0.f;
    for (int c0 = beg; c0 < end; c0 += 64) {
        int cnt = end - c0; if (cnt > 64) cnt = 64;
        int ids = (c0 + lane < end) ? esrc[c0 + lane] : 0;
        int t = 0;
        for (; t + 3 < cnt; t += 4) {   // 4 gathers in flight
            int sa = __shfl(ids, t);
            int sb = __shfl(ids, t + 1);
            int sc = __shfl(ids, t + 2);
            int sd = __shfl(ids, t + 3);
            unsigned pa = *(const unsigned*)(Yb + (size_t)sa * HID + lane * 2);
            unsigned pb = *(const unsigned*)(Yb + (size_t)sb * HID + lane * 2);
            unsigned pc = *(const unsigned*)(Yb + (size_t)sc * HID + lane * 2);
            unsigned pd = *(const unsigned*)(Yb + (size_t)sd * HID + lane * 2);
            s0 += bflo(pa) + bflo(pb) + bflo(pc) + bflo(pd);
            s1 += bfhi(pa) + bfhi(pb) + bfhi(pc) + bfhi(pd);
        }
        for (; t < cnt; t++) {
            int sa = __shfl(ids, t);
            unsigned pa = *(const unsigned*)(Yb + (size_t)sa * HID + lane * 2);
            s0 += bflo(pa);
            s1 += bfhi(pa);
        }
    }
    float inv = 1.0f / fmaxf((float)(end - beg), 1.0f);
    size_t base = (size_t)node * HID;
    float2 b2 = *(const float2*)(bias + 2 * lane);
    unsigned r2 = *(const unsigned*)(Rm + base + 2 * lane);
    float v0 = s0 * inv + b2.x + bflo(r2);
    float v1 = s1 * inv + b2.y + bfhi(r2);
    float o0, o1;
    if (mode == 0) {
        o0 = fmaxf(v0, 0.f);
        o1 = fmaxf(v1, 0.f);
    } else {
        unsigned h2 = *(const unsigned*)(Hres + base + 2 * lane);
        float z0 = v0 + bflo(h2);
        float z1 = v1 + bfhi(h2);
        float sum = z0 + z1;
#pragma unroll
        for (int off = 32; off; off >>= 1) sum += __shfl_xor(sum, off);
        float mu = sum * (1.f / 128.f);
        float d0 = z0 - mu, d1 = z1 - mu;
        float vs = d0 * d0 + d1 * d1;
#pragma unroll
        for (int off = 32; off; off >>= 1) vs += __shfl_xor(vs, off);
        float rstd = rsqrtf(vs * (1.f / 128.f) + 1e-5f);
        o0 = fmaxf(d0 * rstd, 0.f);
        o1 = fmaxf(d1 * rstd, 0.f);
    }
    if (mode == 2) {
        float2 w0 = *(const float2*)(lW + 2 * lane);
        float2 w1 = *(const float2*)(lW + 128 + 2 * lane);
        float p0 = o0 * w0.x + o1 * w0.y;
        float p1 = o0 * w1.x + o1 * w1.y;
#pragma unroll
        for (int off = 32; off; off >>= 1) {
            p0 += __shfl_xor(p0, off);
            p1 += __shfl_xor(p1, off);
        }
        if (lane == 0) {
            out[(size_t)node * 2 + 0] = p0 + lb[0];
            out[(size_t)node * 2 + 1] = p1 + lb[1];
        }
    } else {
        unsigned pk = (unsigned)f2bf(o0) | ((unsigned)f2bf(o1) << 16);
        *(unsigned*)(HbOut + base + 2 * lane) = pk;
    }
}

extern "C" void kernel_launch(void* const* d_in, const int* in_sizes, int n_in,
                              void* d_out, int out_size, void* d_ws, size_t ws_size,
                              hipStream_t stream) {
    const int N = N_NODES, E = N_EDGES;
    const float* x   = (const float*)d_in[0];
    const int*   ei  = (const int*)d_in[1];
    const float* Wl0 = (const float*)d_in[2];
    const float* bl0 = (const float*)d_in[3];
    const float* Wr0 = (const float*)d_in[4];
    const float* Wl  = (const float*)d_in[5];
    const float* bl  = (const float*)d_in[6];
    const float* Wr  = (const float*)d_in[7];
    const float* lW  = (const float*)d_in[8];
    const float* lb  = (const float*)d_in[9];
    float* out = (float*)d_out;

    const int* src = ei;
    const int* dst = ei + E;

    const int PADR = 64;

    char* w = (char*)d_ws;
    ushort* Yb  = (ushort*)w; w += (size_t)(N + PADR) * HID * sizeof(ushort);
    ushort* Rb  = (ushort*)w; w += (size_t)N * HID * sizeof(ushort);
    ushort* Hb  = (ushort*)w; w += (size_t)(N + PADR) * HID * sizeof(ushort);
    short*  Wb0 = (short*)w;  w += (size_t)256 * KP0 * sizeof(short);
    short*  Wb12= (short*)w;  w += (size_t)2 * 256 * HID * sizeof(short);
    int* counts = (int*)w;    w += (size_t)NBLK1 * NBKT * sizeof(int);
    int* offs   = (int*)w;    w += (size_t)NBLK1 * NBKT * sizeof(int);
    int* counts2= (int*)w;    w += (size_t)NBLK1 * NSB * sizeof(int);
    int* offs2  = (int*)w;    w += (size_t)NBLK1 * NSB * sizeof(int);
    int* bbase  = (int*)w;    w += (size_t)NBKT * sizeof(int);
    int* rowptr = (int*)w;    w += (size_t)(N + 1) * sizeof(int);
    int* ebuf   = (int*)w;    w += (size_t)E * sizeof(int);
    int* esrc   = (int*)w;    w += (size_t)E * sizeof(int);
    int2* ebuf2 = (int2*)w;   w += (size_t)E * sizeof(int2);

    const int nbGemm = (N + 63) / 64;
    const int nbNode = (N + 3) / 4;

    // src-bucket pre-sort, then stable dst counting sort -> CSR with src-bucket-ordered lists
    k_s1<<<NBLK1, 256, 0, stream>>>(src, counts2, E);
    k_s2<<<1, 64, 0, stream>>>(counts2, offs2);
    k_s3<<<NBLK1, 256, 0, stream>>>(src, dst, offs2, ebuf2, E);
    k_p1<<<NBLK1, 256, 0, stream>>>(ebuf2, counts, E);
    k_p2<<<1, 256, 0, stream>>>(counts, offs, bbase, rowptr, E);
    k_p3<<<NBLK1, 256, 0, stream>>>(ebuf2, offs, ebuf, E);
    k_p4<<<NBKT, 256, 0, stream>>>(ebuf, bbase, rowptr, esrc, E, N);

    // weight casts (tiny)
    k_cast_w0<<<(256 * KP0 + 255) / 256, 256, 0, stream>>>(Wl0, Wr0, Wb0);
    k_cast_w12<<<(2 * 256 * HID + 255) / 256, 256, 0, stream>>>(Wl, Wr, Wb12);

    // layer 0 (A = x, f32, cast fused into fragment load)
    k_gemm_mfma<KP0, F_IN, true><<<nbGemm, 256, 0, stream>>>(x, Wb0, Yb, Rb, N);
    k_aggregate<<<nbNode, 256, 0, stream>>>(Yb, Rb, nullptr, rowptr, esrc, bl0, Hb,
                                            nullptr, nullptr, nullptr, N, 0);

    // layer 1
    k_gemm_mfma<HID, HID, false><<<nbGemm, 256, 0, stream>>>(Hb, Wb12, Yb, Rb, N);
    k_aggregate<<<nbNode, 256, 0, stream>>>(Yb, Rb, Hb, rowptr, esrc, bl, Hb,
                                            nullptr, nullptr, nullptr, N, 1);

    // layer 2 + fused final projection
    k_gemm_mfma<HID, HID, false><<<nbGemm, 256, 0, stream>>>(Hb, Wb12 + 256 * HID, Yb, Rb, N);
    k_aggregate<<<nbNode, 256, 0, stream>>>(Yb, Rb, Hb, rowptr, esrc, bl + HID, nullptr,
                                            lW, lb, out, N, 2);
}

// Round 6
// 458.712 us; speedup vs baseline: 6.6816x; 1.1124x over previous
//
#include <hip/hip_runtime.h>
#include <hip/hip_bf16.h>

#define N_NODES 100000
#define N_EDGES 1600000
#define F_IN 165
#define KP0 192   // F_IN padded to multiple of 32
#define HID 128

#define NBKT 196   // ceil(N/512) coarse dst buckets (dst>>9)
#define EPB1 8192  // edges per block in coarse passes
#define NBLK1 196  // ceil(E/EPB1)
#define NSB 13     // src buckets (src>>13, 8192-node = 2MB stripes)

typedef __attribute__((ext_vector_type(8))) short bf16x8;
typedef __attribute__((ext_vector_type(4))) float f32x4;

__device__ __forceinline__ ushort f2bf(float f) {
    unsigned u = __float_as_uint(f);
    unsigned r = (u + 0x7fffu + ((u >> 16) & 1u)) >> 16;  // RNE
    return (ushort)r;
}
__device__ __forceinline__ float bflo(unsigned p) { return __uint_as_float(p << 16); }
__device__ __forceinline__ float bfhi(unsigned p) { return __uint_as_float(p & 0xffff0000u); }

// ---------------- src-bucket pre-sort (for gather L2 locality) ----------------

__global__ __launch_bounds__(256) void k_s1(const int* __restrict__ src, int* __restrict__ counts2, int E) {
    __shared__ int h[NSB];
    int t = threadIdx.x;
    if (t < NSB) h[t] = 0;
    __syncthreads();
    int base = blockIdx.x * EPB1;
    for (int i = 0; i < EPB1; i += 256) {
        int e = base + i + t;
        if (e < E) atomicAdd(&h[src[e] >> 13], 1);
    }
    __syncthreads();
    if (t < NSB) counts2[blockIdx.x * NSB + t] = h[t];
}

__global__ __launch_bounds__(64) void k_s2(const int* __restrict__ counts2, int* __restrict__ offs2) {
    __shared__ int tot[NSB], base[NSB];
    int t = threadIdx.x;
    if (t < NSB) {
        int s = 0;
        for (int b = 0; b < NBLK1; b++) s += counts2[b * NSB + t];
        tot[t] = s;
    }
    __syncthreads();
    if (t == 0) {
        int run = 0;
        for (int i = 0; i < NSB; i++) { base[i] = run; run += tot[i]; }
    }
    __syncthreads();
    if (t < NSB) {
        int run = base[t];
        for (int b = 0; b < NBLK1; b++) {
            offs2[b * NSB + t] = run;
            run += counts2[b * NSB + t];
        }
    }
}

__global__ __launch_bounds__(256) void k_s3(const int* __restrict__ src, const int* __restrict__ dst,
                                            const int* __restrict__ offs2, int2* __restrict__ ebuf2, int E) {
    __shared__ int cur[NSB];
    int t = threadIdx.x;
    if (t < NSB) cur[t] = offs2[blockIdx.x * NSB + t];
    __syncthreads();
    int base = blockIdx.x * EPB1;
    for (int i = 0; i < EPB1; i += 256) {
        int e = base + i + t;
        if (e < E) {
            int s = src[e], d = dst[e];
            int pos = atomicAdd(&cur[s >> 13], 1);
            ebuf2[pos] = make_int2(s, d);
        }
    }
}

// ---------------- CSR build via 2-level counting sort (stable over src order) ----------------

__global__ __launch_bounds__(256) void k_p1(const int2* __restrict__ ebuf2, int* __restrict__ counts, int E) {
    __shared__ int h[NBKT];
    int t = threadIdx.x;
    for (int i = t; i < NBKT; i += 256) h[i] = 0;
    __syncthreads();
    int base = blockIdx.x * EPB1;
    for (int i = 0; i < EPB1; i += 256) {
        int e = base + i + t;
        if (e < E) atomicAdd(&h[ebuf2[e].y >> 9], 1);
    }
    __syncthreads();
    for (int i = t; i < NBKT; i += 256) counts[blockIdx.x * NBKT + i] = h[i];
}

__global__ __launch_bounds__(256) void k_p2(const int* __restrict__ counts, int* __restrict__ offs,
                                            int* __restrict__ bbase, int* __restrict__ rowptr, int E) {
    __shared__ int s[256];
    int t = threadIdx.x;
    int tot = 0;
    if (t < NBKT) {
        for (int blk = 0; blk < NBLK1; blk++) tot += counts[blk * NBKT + t];
    }
    s[t] = (t < NBKT) ? tot : 0;
    __syncthreads();
    for (int off = 1; off < 256; off <<= 1) {
        int v = (t >= off) ? s[t - off] : 0;
        __syncthreads();
        s[t] += v;
        __syncthreads();
    }
    int base = s[t] - tot;  // exclusive
    if (t < NBKT) {
        bbase[t] = base;
        int run = base;
        for (int blk = 0; blk < NBLK1; blk++) {
            int c = counts[blk * NBKT + t];
            offs[blk * NBKT + t] = run;
            run += c;
        }
    }
    if (t == 0) rowptr[N_NODES] = E;
}

__global__ __launch_bounds__(256) void k_p3(const int2* __restrict__ ebuf2,
                                            const int* __restrict__ offs, int* __restrict__ ebuf, int E) {
    __shared__ int cur[NBKT];
    int t = threadIdx.x;
    for (int i = t; i < NBKT; i += 256) cur[i] = offs[blockIdx.x * NBKT + i];
    __syncthreads();
    int base = blockIdx.x * EPB1;
    for (int i = 0; i < EPB1; i += 256) {
        int e = base + i + t;
        if (e < E) {
            int2 ed = ebuf2[e];
            int b = ed.y >> 9;
            int pos = atomicAdd(&cur[b], 1);
            ebuf[pos] = ed.x | ((ed.y & 511) << 17);
        }
    }
}

__global__ __launch_bounds__(256) void k_p4(const int* __restrict__ ebuf, const int* __restrict__ bbase,
                                            int* __restrict__ rowptr, int* __restrict__ esrc, int E, int N) {
    __shared__ int fh[512], fex[512], fcur[512];
    __shared__ int sc[256];
    int t = threadIdx.x;
    int b = blockIdx.x;
    int base = bbase[b];
    int end = (b + 1 < NBKT) ? bbase[b + 1] : E;
    int cnt = end - base;
    fh[t] = 0; fh[t + 256] = 0; fcur[t] = 0; fcur[t + 256] = 0;
    __syncthreads();
    for (int i = t; i < cnt; i += 256) atomicAdd(&fh[(ebuf[base + i] >> 17) & 511], 1);
    __syncthreads();
    int a0 = fh[2 * t], a1 = fh[2 * t + 1];
    sc[t] = a0 + a1;
    __syncthreads();
    for (int off = 1; off < 256; off <<= 1) {
        int v = (t >= off) ? sc[t - off] : 0;
        __syncthreads();
        sc[t] += v;
        __syncthreads();
    }
    int ex = sc[t] - (a0 + a1);
    fex[2 * t] = ex;
    fex[2 * t + 1] = ex + a0;
    __syncthreads();
    int node0 = b << 9;
    for (int f = t; f < 512; f += 256) {
        int node = node0 + f;
        if (node < N) rowptr[node] = base + fex[f];
    }
    for (int i = t; i < cnt; i += 256) {
        int p = ebuf[base + i];
        int f = (p >> 17) & 511;
        int pos = base + fex[f] + atomicAdd(&fcur[f], 1);
        esrc[pos] = p & 0x1ffff;
    }
}

// ---------------- casts ----------------

// x [N,165] f32 -> xb [N+pad,192] bf16, 8 elems per thread, 16B packed writes
__global__ __launch_bounds__(256) void k_cast_x(const float* __restrict__ x, ushort* __restrict__ xb, int NP) {
    int idx = blockIdx.x * 256 + threadIdx.x;        // NP*24 threads
    if (idx >= NP * (KP0 / 8)) return;
    int row = idx / (KP0 / 8), j = idx % (KP0 / 8);
    int c0 = j * 8;
    ushort pk[8];
#pragma unroll
    for (int i = 0; i < 8; i++) {
        int c = c0 + i;
        float v = (row < N_NODES && c < F_IN) ? x[(size_t)row * F_IN + c] : 0.f;
        pk[i] = f2bf(v);
    }
    *(uint4*)(xb + (size_t)row * KP0 + c0) = *(uint4*)pk;
}

__global__ __launch_bounds__(256) void k_cast_w0(const float* __restrict__ Wl, const float* __restrict__ Wr,
                                                 short* __restrict__ Wb) {
    int idx = blockIdx.x * 256 + threadIdx.x;
    if (idx >= 256 * KP0) return;
    int row = idx / KP0, col = idx % KP0;
    const float* W = (row < 128) ? Wl : Wr;
    float v = (col < F_IN) ? W[(size_t)(row & 127) * F_IN + col] : 0.f;
    Wb[idx] = (short)f2bf(v);
}

__global__ __launch_bounds__(256) void k_cast_w12(const float* __restrict__ Wl, const float* __restrict__ Wr,
                                                  short* __restrict__ Wb) {
    int idx = blockIdx.x * 256 + threadIdx.x;
    if (idx >= 2 * 256 * HID) return;
    int layer = idx / (256 * HID);
    int rem = idx % (256 * HID);
    int row = rem / HID, col = rem % HID;
    const float* W = (row < 128) ? Wl : Wr;
    float v = W[(size_t)layer * HID * HID + (size_t)(row & 127) * HID + col];
    Wb[idx] = (short)f2bf(v);
}

// ---------------- register-tiled MFMA dual GEMM ----------------
// A bf16 [Mpad][KPV] (Mpad mult of 64), W bf16 [256][KPV]
// Block: 64 rows x 256 cols; wave w: 64 rows x cols [w*64, w*64+64).
// Per K-step: 4 A-frags + 4 B-frags -> 16 independent MFMAs (4x4 reg tile).
template <int KPV>
__global__ __launch_bounds__(256) void k_gemm_rt(
    const short* __restrict__ A, const short* __restrict__ W,
    ushort* __restrict__ Yb, ushort* __restrict__ Rb, int M)
{
    constexpr int NK = KPV / 32;
    int wave = threadIdx.x >> 6;
    int lane = threadIdx.x & 63;
    int lr = lane & 15;
    int kg = lane >> 4;
    int m0 = blockIdx.x * 64;
    int wc = wave * 64;   // first output col of this wave

    f32x4 acc[4][4];
#pragma unroll
    for (int i = 0; i < 4; i++)
#pragma unroll
        for (int j = 0; j < 4; j++) acc[i][j] = {0.f, 0.f, 0.f, 0.f};

    const short* abase = A + (size_t)(m0 + lr) * KPV + kg * 8;
    const short* wbase = W + (size_t)(wc + lr) * KPV + kg * 8;

#pragma unroll
    for (int ks = 0; ks < NK; ks++) {
        bf16x8 a[4], b[4];
#pragma unroll
        for (int rt = 0; rt < 4; rt++)
            a[rt] = *(const bf16x8*)(abase + (size_t)rt * 16 * KPV + ks * 32);
#pragma unroll
        for (int ntl = 0; ntl < 4; ntl++)
            b[ntl] = *(const bf16x8*)(wbase + (size_t)ntl * 16 * KPV + ks * 32);
#pragma unroll
        for (int rt = 0; rt < 4; rt++)
#pragma unroll
            for (int ntl = 0; ntl < 4; ntl++)
                acc[rt][ntl] = __builtin_amdgcn_mfma_f32_16x16x32_bf16(a[rt], b[ntl], acc[rt][ntl], 0, 0, 0);
    }

    // store: pack adjacent-col pairs via shfl_xor(1) -> dword stores on even-lr lanes
#pragma unroll
    for (int rt = 0; rt < 4; rt++) {
#pragma unroll
        for (int ntl = 0; ntl < 4; ntl++) {
            int c = wc + ntl * 16 + lr;
#pragma unroll
            for (int r = 0; r < 4; r++) {
                float v = acc[rt][ntl][r];
                float vp = __shfl_xor(v, 1);
                unsigned pk = (unsigned)f2bf(v) | ((unsigned)f2bf(vp) << 16);
                int node = m0 + rt * 16 + kg * 4 + r;
                if (!(lr & 1) && node < M) {
                    ushort* dstp = (c < HID) ? (Yb + (size_t)node * HID + c)
                                             : (Rb + (size_t)node * HID + (c - HID));
                    *(unsigned*)dstp = pk;
                }
            }
        }
    }
}

// ---------------- fused aggregate + bias + root + (LN) + ReLU (+ final proj) ----------------
__global__ __launch_bounds__(256) void k_aggregate(
    const ushort* __restrict__ Yb, const ushort* __restrict__ Rm,
    const ushort* __restrict__ Hres,
    const int* __restrict__ rowptr, const int* __restrict__ esrc,
    const float* __restrict__ bias, ushort* __restrict__ HbOut,
    const float* __restrict__ lW, const float* __restrict__ lb,
    float* __restrict__ out, int N, int mode)
{
    int lane = threadIdx.x & 63;
    int node = blockIdx.x * 4 + (threadIdx.x >> 6);
    if (node >= N) return;
    int beg = rowptr[node], end = rowptr[node + 1];
    float s0 = 0.f, s1 = 0.f;
    for (int c0 = beg; c0 < end; c0 += 64) {
        int cnt = end - c0; if (cnt > 64) cnt = 64;
        int ids = (c0 + lane < end) ? esrc[c0 + lane] : 0;
        int t = 0;
        for (; t + 3 < cnt; t += 4) {   // 4 gathers in flight
            int sa = __shfl(ids, t);
            int sb = __shfl(ids, t + 1);
            int sc = __shfl(ids, t + 2);
            int sd = __shfl(ids, t + 3);
            unsigned pa = *(const unsigned*)(Yb + (size_t)sa * HID + lane * 2);
            unsigned pb = *(const unsigned*)(Yb + (size_t)sb * HID + lane * 2);
            unsigned pc = *(const unsigned*)(Yb + (size_t)sc * HID + lane * 2);
            unsigned pd = *(const unsigned*)(Yb + (size_t)sd * HID + lane * 2);
            s0 += bflo(pa) + bflo(pb) + bflo(pc) + bflo(pd);
            s1 += bfhi(pa) + bfhi(pb) + bfhi(pc) + bfhi(pd);
        }
        for (; t < cnt; t++) {
            int sa = __shfl(ids, t);
            unsigned pa = *(const unsigned*)(Yb + (size_t)sa * HID + lane * 2);
            s0 += bflo(pa);
            s1 += bfhi(pa);
        }
    }
    float inv = 1.0f / fmaxf((float)(end - beg), 1.0f);
    size_t base = (size_t)node * HID;
    float2 b2 = *(const float2*)(bias + 2 * lane);
    unsigned r2 = *(const unsigned*)(Rm + base + 2 * lane);
    float v0 = s0 * inv + b2.x + bflo(r2);
    float v1 = s1 * inv + b2.y + bfhi(r2);
    float o0, o1;
    if (mode == 0) {
        o0 = fmaxf(v0, 0.f);
        o1 = fmaxf(v1, 0.f);
    } else {
        unsigned h2 = *(const unsigned*)(Hres + base + 2 * lane);
        float z0 = v0 + bflo(h2);
        float z1 = v1 + bfhi(h2);
        float sum = z0 + z1;
#pragma unroll
        for (int off = 32; off; off >>= 1) sum += __shfl_xor(sum, off);
        float mu = sum * (1.f / 128.f);
        float d0 = z0 - mu, d1 = z1 - mu;
        float vs = d0 * d0 + d1 * d1;
#pragma unroll
        for (int off = 32; off; off >>= 1) vs += __shfl_xor(vs, off);
        float rstd = rsqrtf(vs * (1.f / 128.f) + 1e-5f);
        o0 = fmaxf(d0 * rstd, 0.f);
        o1 = fmaxf(d1 * rstd, 0.f);
    }
    if (mode == 2) {
        float2 w0 = *(const float2*)(lW + 2 * lane);
        float2 w1 = *(const float2*)(lW + 128 + 2 * lane);
        float p0 = o0 * w0.x + o1 * w0.y;
        float p1 = o0 * w1.x + o1 * w1.y;
#pragma unroll
        for (int off = 32; off; off >>= 1) {
            p0 += __shfl_xor(p0, off);
            p1 += __shfl_xor(p1, off);
        }
        if (lane == 0) {
            out[(size_t)node * 2 + 0] = p0 + lb[0];
            out[(size_t)node * 2 + 1] = p1 + lb[1];
        }
    } else {
        unsigned pk = (unsigned)f2bf(o0) | ((unsigned)f2bf(o1) << 16);
        *(unsigned*)(HbOut + base + 2 * lane) = pk;
    }
}

extern "C" void kernel_launch(void* const* d_in, const int* in_sizes, int n_in,
                              void* d_out, int out_size, void* d_ws, size_t ws_size,
                              hipStream_t stream) {
    const int N = N_NODES, E = N_EDGES;
    const float* x   = (const float*)d_in[0];
    const int*   ei  = (const int*)d_in[1];
    const float* Wl0 = (const float*)d_in[2];
    const float* bl0 = (const float*)d_in[3];
    const float* Wr0 = (const float*)d_in[4];
    const float* Wl  = (const float*)d_in[5];
    const float* bl  = (const float*)d_in[6];
    const float* Wr  = (const float*)d_in[7];
    const float* lW  = (const float*)d_in[8];
    const float* lb  = (const float*)d_in[9];
    float* out = (float*)d_out;

    const int* src = ei;
    const int* dst = ei + E;

    const int PADR = 64;
    const int NP = ((N + 63) / 64) * 64;  // rows covered by GEMM grid (<= N+PADR)

    char* w = (char*)d_ws;
    ushort* Yb  = (ushort*)w; w += (size_t)(N + PADR) * HID * sizeof(ushort);
    ushort* Rb  = (ushort*)w; w += (size_t)(N + PADR) * HID * sizeof(ushort);
    ushort* Hb  = (ushort*)w; w += (size_t)(N + PADR) * HID * sizeof(ushort);
    ushort* xb  = (ushort*)w; w += (size_t)(N + PADR) * KP0 * sizeof(ushort);
    short*  Wb0 = (short*)w;  w += (size_t)256 * KP0 * sizeof(short);
    short*  Wb12= (short*)w;  w += (size_t)2 * 256 * HID * sizeof(short);
    int* counts = (int*)w;    w += (size_t)NBLK1 * NBKT * sizeof(int);
    int* offs   = (int*)w;    w += (size_t)NBLK1 * NBKT * sizeof(int);
    int* counts2= (int*)w;    w += (size_t)NBLK1 * NSB * sizeof(int);
    int* offs2  = (int*)w;    w += (size_t)NBLK1 * NSB * sizeof(int);
    int* bbase  = (int*)w;    w += (size_t)NBKT * sizeof(int);
    int* rowptr = (int*)w;    w += (size_t)(N + 1) * sizeof(int);
    int* ebuf   = (int*)w;    w += (size_t)E * sizeof(int);
    int* esrc   = (int*)w;    w += (size_t)E * sizeof(int);
    int2* ebuf2 = (int2*)w;   w += (size_t)E * sizeof(int2);

    const int nbGemm = (N + 63) / 64;
    const int nbNode = (N + 3) / 4;

    // src-bucket pre-sort, then stable dst counting sort -> CSR with src-bucket-ordered lists
    k_s1<<<NBLK1, 256, 0, stream>>>(src, counts2, E);
    k_s2<<<1, 64, 0, stream>>>(counts2, offs2);
    k_s3<<<NBLK1, 256, 0, stream>>>(src, dst, offs2, ebuf2, E);
    k_p1<<<NBLK1, 256, 0, stream>>>(ebuf2, counts, E);
    k_p2<<<1, 256, 0, stream>>>(counts, offs, bbase, rowptr, E);
    k_p3<<<NBLK1, 256, 0, stream>>>(ebuf2, offs, ebuf, E);
    k_p4<<<NBKT, 256, 0, stream>>>(ebuf, bbase, rowptr, esrc, E, N);

    // casts
    k_cast_x<<<(NP * (KP0 / 8) + 255) / 256, 256, 0, stream>>>(x, xb, NP);
    k_cast_w0<<<(256 * KP0 + 255) / 256, 256, 0, stream>>>(Wl0, Wr0, Wb0);
    k_cast_w12<<<(2 * 256 * HID + 255) / 256, 256, 0, stream>>>(Wl, Wr, Wb12);

    // layer 0
    k_gemm_rt<KP0><<<nbGemm, 256, 0, stream>>>((const short*)xb, Wb0, Yb, Rb, N);
    k_aggregate<<<nbNode, 256, 0, stream>>>(Yb, Rb, nullptr, rowptr, esrc, bl0, Hb,
                                            nullptr, nullptr, nullptr, N, 0);

    // layer 1
    k_gemm_rt<HID><<<nbGemm, 256, 0, stream>>>((const short*)Hb, Wb12, Yb, Rb, N);
    k_aggregate<<<nbNode, 256, 0, stream>>>(Yb, Rb, Hb, rowptr, esrc, bl, Hb,
                                            nullptr, nullptr, nullptr, N, 1);

    // layer 2 + fused final projection
    k_gemm_rt<HID><<<nbGemm, 256, 0, stream>>>((const short*)Hb, Wb12 + 256 * HID, Yb, Rb, N);
    k_aggregate<<<nbNode, 256, 0, stream>>>(Yb, Rb, Hb, rowptr, esrc, bl + HID, nullptr,
                                            lW, lb, out, N, 2);
}